// Round 1
// baseline (205.940 us; speedup 1.0000x reference)
//
#include <hip/hip_runtime.h>
#include <hip/hip_bf16.h>

#define SELU_L 1.0507009873554805f
#define SELU_A 1.6732632423543772f

__device__ __forceinline__ float selu(float x) {
    return x > 0.f ? SELU_L * x : SELU_L * SELU_A * (expf(x) - 1.f);
}

// ---------------- Kernel A: o1 = selu(x @ fc_w^T + fc_b) --------------------
// x: [8192, 784], fc_w: [128, 784], o1: [8192, 128]
// BM=64, BN=64, BK=16, 256 threads (16x16), 4x4 per thread.
__global__ __launch_bounds__(256) void gemm1_selu(
    const float* __restrict__ x, const float* __restrict__ w,
    const float* __restrict__ b, float* __restrict__ o1)
{
    __shared__ float As[16][68];
    __shared__ float Bs[16][68];
    const int bm = blockIdx.x * 64;
    const int bn = blockIdx.y * 64;
    const int t  = threadIdx.x;
    const int tx = t % 16, ty = t / 16;

    const int lrow  = t / 4;        // 0..63
    const int lcol4 = (t % 4) * 4;  // 0,4,8,12

    float acc[4][4] = {};

    for (int k0 = 0; k0 < 784; k0 += 16) {
        float4 av = *reinterpret_cast<const float4*>(&x[(size_t)(bm + lrow) * 784 + k0 + lcol4]);
        float4 bv = *reinterpret_cast<const float4*>(&w[(size_t)(bn + lrow) * 784 + k0 + lcol4]);
        As[lcol4 + 0][lrow] = av.x;
        As[lcol4 + 1][lrow] = av.y;
        As[lcol4 + 2][lrow] = av.z;
        As[lcol4 + 3][lrow] = av.w;
        Bs[lcol4 + 0][lrow] = bv.x;
        Bs[lcol4 + 1][lrow] = bv.y;
        Bs[lcol4 + 2][lrow] = bv.z;
        Bs[lcol4 + 3][lrow] = bv.w;
        __syncthreads();
#pragma unroll
        for (int kk = 0; kk < 16; ++kk) {
            float a[4], bb[4];
#pragma unroll
            for (int i = 0; i < 4; ++i) a[i] = As[kk][ty * 4 + i];
#pragma unroll
            for (int j = 0; j < 4; ++j) bb[j] = Bs[kk][tx * 4 + j];
#pragma unroll
            for (int i = 0; i < 4; ++i)
#pragma unroll
                for (int j = 0; j < 4; ++j)
                    acc[i][j] = fmaf(a[i], bb[j], acc[i][j]);
        }
        __syncthreads();
    }

#pragma unroll
    for (int i = 0; i < 4; ++i) {
        const int r = bm + ty * 4 + i;
#pragma unroll
        for (int j = 0; j < 4; ++j) {
            const int h = bn + tx * 4 + j;
            o1[(size_t)r * 128 + h] = selu(acc[i][j] + b[h]);
        }
    }
}

// ---------------- Kernel B: per-column sum / sumsq --------------------------
__global__ __launch_bounds__(256) void bn_stats(
    const float* __restrict__ o1, double* __restrict__ sums, double* __restrict__ sumsq)
{
    const int t   = threadIdx.x;
    const int col = t % 128;
    const int rh  = t / 128;
    const int base = blockIdx.x * 64;
    float s = 0.f, s2 = 0.f;
    for (int r = rh; r < 64; r += 2) {
        float v = o1[(size_t)(base + r) * 128 + col];
        s += v;
        s2 = fmaf(v, v, s2);
    }
    __shared__ float sh[256], sh2[256];
    sh[t] = s; sh2[t] = s2;
    __syncthreads();
    if (rh == 0) {
        s  = sh[t] + sh[t + 128];
        s2 = sh2[t] + sh2[t + 128];
        atomicAdd(&sums[col],  (double)s);
        atomicAdd(&sumsq[col], (double)s2);
    }
}

// ---------------- Kernel C: BN normalize + fc2 + selu, write o & sq ---------
__global__ __launch_bounds__(256) void bn_fc2_selu(
    const float* __restrict__ o1, const double* __restrict__ sums, const double* __restrict__ sumsq,
    const float* __restrict__ gamma, const float* __restrict__ beta,
    const float* __restrict__ fc2w, const float* __restrict__ fc2b,
    float* __restrict__ o_out, float* __restrict__ sq)
{
    const int wave = threadIdx.x >> 6;
    const int lane = threadIdx.x & 63;
    const int row  = blockIdx.x * 4 + wave;

    float d0 = 0.f, d1 = 0.f;
#pragma unroll
    for (int half = 0; half < 2; ++half) {
        const int col = lane + half * 64;
        const float mu  = (float)(sums[col]  * (1.0 / 8192.0));
        const float ex2 = (float)(sumsq[col] * (1.0 / 8192.0));
        const float var = ex2 - mu * mu;
        const float inv = rsqrtf(var + 1e-5f);
        const float v = (o1[(size_t)row * 128 + col] - mu) * inv * gamma[col] + beta[col];
        d0 = fmaf(v, fc2w[col],       d0);
        d1 = fmaf(v, fc2w[128 + col], d1);
    }
#pragma unroll
    for (int off = 32; off >= 1; off >>= 1) {
        d0 += __shfl_down(d0, off);
        d1 += __shfl_down(d1, off);
    }
    if (lane == 0) {
        const float y0 = selu(d0 + fc2b[0]);
        const float y1 = selu(d1 + fc2b[1]);
        o_out[(size_t)row * 2 + 0] = y0;
        o_out[(size_t)row * 2 + 1] = y1;
        sq[row] = y0 * y0 + y1 * y1;
    }
}

// ---------------- Kernel D: denom = sum over all pairs of 1/(1+dis) ---------
// grid (128, 8): 64 rows x 1024 cols per block.
__global__ __launch_bounds__(256) void denom_reduce(
    const float* __restrict__ o, const float* __restrict__ sq, double* __restrict__ denom)
{
    __shared__ float4 colD[1024];
    const int t  = threadIdx.x;
    const int cb = blockIdx.y * 1024;
    for (int c = t; c < 1024; c += 256) {
        float2 oj = *reinterpret_cast<const float2*>(&o[(size_t)(cb + c) * 2]);
        colD[c] = make_float4(oj.x, oj.y, sq[cb + c], 0.f);
    }
    __syncthreads();

    const int rb = blockIdx.x * 64;
    float accf = 0.f;
    for (int r = 0; r < 64; ++r) {
        const int i = rb + r;
        const float oi0 = o[(size_t)i * 2 + 0];
        const float oi1 = o[(size_t)i * 2 + 1];
        const float si  = sq[i];
#pragma unroll
        for (int u = 0; u < 4; ++u) {
            const float4 cd = colD[t + u * 256];
            float dis = si + cd.z - 2.f * fmaf(oi0, cd.x, oi1 * cd.y);
            dis = fmaxf(dis, 0.f);
            accf += 1.f / (1.f + dis);
        }
    }
    // wave reduce (float), then block reduce in double, one atomic per block
#pragma unroll
    for (int off = 32; off >= 1; off >>= 1) accf += __shfl_down(accf, off);
    __shared__ double wsum[4];
    const int wave = t >> 6, lane = t & 63;
    if (lane == 0) wsum[wave] = (double)accf;
    __syncthreads();
    if (t == 0) {
        double v = wsum[0] + wsum[1] + wsum[2] + wsum[3];
        atomicAdd(denom, v);
    }
}

// ---------------- Kernel E: qij = inv_denom / (1 + dis), float4 stores ------
// grid (256, 8): 32 rows x 1024 cols per block.
__global__ __launch_bounds__(256) void qij_write(
    const float* __restrict__ o, const float* __restrict__ sq,
    const double* __restrict__ denom, float* __restrict__ qij)
{
    __shared__ float4 colD[1024];
    const int t  = threadIdx.x;
    const int cb = blockIdx.y * 1024;
    for (int c = t; c < 1024; c += 256) {
        float2 oj = *reinterpret_cast<const float2*>(&o[(size_t)(cb + c) * 2]);
        colD[c] = make_float4(oj.x, oj.y, sq[cb + c], 0.f);
    }
    const float inv = (float)(1.0 / (denom[0] - 8192.0));
    __syncthreads();

    const int rb = blockIdx.x * 32;
    for (int r = 0; r < 32; ++r) {
        const int i = rb + r;
        const float oi0 = o[(size_t)i * 2 + 0];
        const float oi1 = o[(size_t)i * 2 + 1];
        const float si  = sq[i];
        float q[4];
#pragma unroll
        for (int u = 0; u < 4; ++u) {
            const float4 cd = colD[t * 4 + u];
            float dis = si + cd.z - 2.f * fmaf(oi0, cd.x, oi1 * cd.y);
            dis = fmaxf(dis, 0.f);
            q[u] = inv / (1.f + dis);
        }
        *reinterpret_cast<float4*>(&qij[(size_t)i * 8192 + cb + t * 4]) =
            make_float4(q[0], q[1], q[2], q[3]);
    }
}

// ---------------------------------------------------------------------------
extern "C" void kernel_launch(void* const* d_in, const int* in_sizes, int n_in,
                              void* d_out, int out_size, void* d_ws, size_t ws_size,
                              hipStream_t stream)
{
    const float* x      = (const float*)d_in[0];
    const float* fc_w   = (const float*)d_in[1];
    const float* fc_b   = (const float*)d_in[2];
    const float* gamma  = (const float*)d_in[3];
    const float* beta   = (const float*)d_in[4];
    const float* fc2_w  = (const float*)d_in[5];
    const float* fc2_b  = (const float*)d_in[6];

    constexpr int N = 8192;
    constexpr int H = 128;

    float* qij   = (float*)d_out;                          // [N, N]
    float* o_out = (float*)d_out + (size_t)N * N;          // [N, 2]

    char* ws = (char*)d_ws;
    constexpr size_t O1_OFF    = 0;                        // N*H floats = 4 MB
    constexpr size_t SUMS_OFF  = (size_t)N * H * 4;        // 128 doubles
    constexpr size_t SUMSQ_OFF = SUMS_OFF + 128 * 8;
    constexpr size_t DENOM_OFF = SUMSQ_OFF + 128 * 8;
    constexpr size_t SQ_OFF    = DENOM_OFF + 16;           // N floats

    float*  o1    = (float*)(ws + O1_OFF);
    double* sums  = (double*)(ws + SUMS_OFF);
    double* sumsq = (double*)(ws + SUMSQ_OFF);
    double* denom = (double*)(ws + DENOM_OFF);
    float*  sq    = (float*)(ws + SQ_OFF);

    // zero the accumulators (ws is poisoned / stale between calls)
    hipMemsetAsync(ws + SUMS_OFF, 0, 128 * 8 * 2 + 16, stream);

    // A: o1 = selu(x @ fc_w^T + fc_b)
    gemm1_selu<<<dim3(N / 64, H / 64), 256, 0, stream>>>(x, fc_w, fc_b, o1);

    // B: column stats
    bn_stats<<<N / 64, 256, 0, stream>>>(o1, sums, sumsq);

    // C: normalize + fc2 + selu -> o_out, sq
    bn_fc2_selu<<<N / 4, 256, 0, stream>>>(o1, sums, sumsq, gamma, beta, fc2_w, fc2_b, o_out, sq);

    // D: denom = sum over all pairs of 1/(1+dis)
    denom_reduce<<<dim3(N / 64, N / 1024), 256, 0, stream>>>(o_out, sq, denom);

    // E: qij = (1/(denom - N)) / (1 + dis)
    qij_write<<<dim3(N / 32, N / 1024), 256, 0, stream>>>(o_out, sq, denom, qij);
}

// Round 2
// 151.215 us; speedup vs baseline: 1.3619x; 1.3619x over previous
//
#include <hip/hip_runtime.h>
#include <hip/hip_bf16.h>

#define SELU_L 1.0507009873554805f
#define SELU_A 1.6732632423543772f

__device__ __forceinline__ float selu(float x) {
    return x > 0.f ? SELU_L * x : SELU_L * SELU_A * (expf(x) - 1.f);
}

__device__ __forceinline__ float fast_rcp(float x) {
    return __builtin_amdgcn_rcpf(x);
}

// ---------------- Kernel A: o1 = selu(x @ fc_w^T + fc_b) --------------------
// x: [8192, 784], fc_w: [128, 784], o1: [8192, 128]
// BM=64, BN=64, BK=16, 256 threads (16x16), 4x4 per thread.
__global__ __launch_bounds__(256) void gemm1_selu(
    const float* __restrict__ x, const float* __restrict__ w,
    const float* __restrict__ b, float* __restrict__ o1)
{
    __shared__ float As[16][68];
    __shared__ float Bs[16][68];
    const int bm = blockIdx.x * 64;
    const int bn = blockIdx.y * 64;
    const int t  = threadIdx.x;
    const int tx = t % 16, ty = t / 16;

    const int lrow  = t / 4;        // 0..63
    const int lcol4 = (t % 4) * 4;  // 0,4,8,12

    float acc[4][4] = {};

    for (int k0 = 0; k0 < 784; k0 += 16) {
        float4 av = *reinterpret_cast<const float4*>(&x[(size_t)(bm + lrow) * 784 + k0 + lcol4]);
        float4 bv = *reinterpret_cast<const float4*>(&w[(size_t)(bn + lrow) * 784 + k0 + lcol4]);
        As[lcol4 + 0][lrow] = av.x;
        As[lcol4 + 1][lrow] = av.y;
        As[lcol4 + 2][lrow] = av.z;
        As[lcol4 + 3][lrow] = av.w;
        Bs[lcol4 + 0][lrow] = bv.x;
        Bs[lcol4 + 1][lrow] = bv.y;
        Bs[lcol4 + 2][lrow] = bv.z;
        Bs[lcol4 + 3][lrow] = bv.w;
        __syncthreads();
#pragma unroll
        for (int kk = 0; kk < 16; ++kk) {
            float a[4], bb[4];
#pragma unroll
            for (int i = 0; i < 4; ++i) a[i] = As[kk][ty * 4 + i];
#pragma unroll
            for (int j = 0; j < 4; ++j) bb[j] = Bs[kk][tx * 4 + j];
#pragma unroll
            for (int i = 0; i < 4; ++i)
#pragma unroll
                for (int j = 0; j < 4; ++j)
                    acc[i][j] = fmaf(a[i], bb[j], acc[i][j]);
        }
        __syncthreads();
    }

#pragma unroll
    for (int i = 0; i < 4; ++i) {
        const int r = bm + ty * 4 + i;
#pragma unroll
        for (int j = 0; j < 4; ++j) {
            const int h = bn + tx * 4 + j;
            o1[(size_t)r * 128 + h] = selu(acc[i][j] + b[h]);
        }
    }
}

// ---------------- Kernel B: per-column sum / sumsq --------------------------
__global__ __launch_bounds__(256) void bn_stats(
    const float* __restrict__ o1, double* __restrict__ sums, double* __restrict__ sumsq)
{
    const int t   = threadIdx.x;
    const int col = t % 128;
    const int rh  = t / 128;
    const int base = blockIdx.x * 64;
    float s = 0.f, s2 = 0.f;
    for (int r = rh; r < 64; r += 2) {
        float v = o1[(size_t)(base + r) * 128 + col];
        s += v;
        s2 = fmaf(v, v, s2);
    }
    __shared__ float sh[256], sh2[256];
    sh[t] = s; sh2[t] = s2;
    __syncthreads();
    if (rh == 0) {
        s  = sh[t] + sh[t + 128];
        s2 = sh2[t] + sh2[t + 128];
        atomicAdd(&sums[col],  (double)s);
        atomicAdd(&sumsq[col], (double)s2);
    }
}

// ---------------- Kernel C: BN normalize + fc2 + selu -----------------------
// writes o_out [N,2] (tail of d_out) and packed [N] float4 = (o0, o1, sq, 0)
__global__ __launch_bounds__(256) void bn_fc2_selu(
    const float* __restrict__ o1, const double* __restrict__ sums, const double* __restrict__ sumsq,
    const float* __restrict__ gamma, const float* __restrict__ beta,
    const float* __restrict__ fc2w, const float* __restrict__ fc2b,
    float* __restrict__ o_out, float4* __restrict__ packed)
{
    const int wave = threadIdx.x >> 6;
    const int lane = threadIdx.x & 63;
    const int row  = blockIdx.x * 4 + wave;

    float d0 = 0.f, d1 = 0.f;
#pragma unroll
    for (int half = 0; half < 2; ++half) {
        const int col = lane + half * 64;
        const float mu  = (float)(sums[col]  * (1.0 / 8192.0));
        const float ex2 = (float)(sumsq[col] * (1.0 / 8192.0));
        const float var = ex2 - mu * mu;
        const float inv = rsqrtf(var + 1e-5f);
        const float v = (o1[(size_t)row * 128 + col] - mu) * inv * gamma[col] + beta[col];
        d0 = fmaf(v, fc2w[col],       d0);
        d1 = fmaf(v, fc2w[128 + col], d1);
    }
#pragma unroll
    for (int off = 32; off >= 1; off >>= 1) {
        d0 += __shfl_down(d0, off);
        d1 += __shfl_down(d1, off);
    }
    if (lane == 0) {
        const float y0 = selu(d0 + fc2b[0]);
        const float y1 = selu(d1 + fc2b[1]);
        o_out[(size_t)row * 2 + 0] = y0;
        o_out[(size_t)row * 2 + 1] = y1;
        packed[row] = make_float4(y0, y1, y0 * y0 + y1 * y1, 0.f);
    }
}

// ---------------- Kernel D: denom = sum over all pairs of 1/(1+dis) ---------
// grid (128, 8): 64 rows x 1024 cols per block. Column data in REGISTERS.
__global__ __launch_bounds__(256) void denom_reduce(
    const float4* __restrict__ packed, double* __restrict__ denom)
{
    const int t  = threadIdx.x;
    const int cb = blockIdx.y * 1024;

    float4 cd[4];
#pragma unroll
    for (int u = 0; u < 4; ++u) cd[u] = packed[cb + t + u * 256];

    const int rb = blockIdx.x * 64;
    float accf = 0.f;
#pragma unroll 4
    for (int r = 0; r < 64; ++r) {
        const float4 pi = packed[rb + r];   // uniform address -> scalar load
#pragma unroll
        for (int u = 0; u < 4; ++u) {
            float dis = pi.z + cd[u].z - 2.f * fmaf(pi.x, cd[u].x, pi.y * cd[u].y);
            dis = fmaxf(dis, 0.f);
            accf += fast_rcp(1.f + dis);
        }
    }
    // wave reduce (float), then block reduce in double, one atomic per block
#pragma unroll
    for (int off = 32; off >= 1; off >>= 1) accf += __shfl_down(accf, off);
    __shared__ double wsum[4];
    const int wave = t >> 6, lane = t & 63;
    if (lane == 0) wsum[wave] = (double)accf;
    __syncthreads();
    if (t == 0) {
        double v = wsum[0] + wsum[1] + wsum[2] + wsum[3];
        atomicAdd(denom, v);
    }
}

// ---------------- Kernel E: qij = inv_denom / (1 + dis), float4 stores ------
// grid (256, 8): 32 rows x 1024 cols per block. Column data in REGISTERS.
__global__ __launch_bounds__(256) void qij_write(
    const float4* __restrict__ packed, const double* __restrict__ denom,
    float* __restrict__ qij)
{
    const int t  = threadIdx.x;
    const int cb = blockIdx.y * 1024;

    float4 cd[4];
#pragma unroll
    for (int u = 0; u < 4; ++u) cd[u] = packed[cb + t * 4 + u];

    const float inv = (float)(1.0 / (denom[0] - 8192.0));

    const int rb = blockIdx.x * 32;
#pragma unroll 4
    for (int r = 0; r < 32; ++r) {
        const int i = rb + r;
        const float4 pi = packed[i];        // uniform address -> scalar load
        float q[4];
#pragma unroll
        for (int u = 0; u < 4; ++u) {
            float dis = pi.z + cd[u].z - 2.f * fmaf(pi.x, cd[u].x, pi.y * cd[u].y);
            dis = fmaxf(dis, 0.f);
            q[u] = inv * fast_rcp(1.f + dis);
        }
        *reinterpret_cast<float4*>(&qij[(size_t)i * 8192 + cb + t * 4]) =
            make_float4(q[0], q[1], q[2], q[3]);
    }
}

// ---------------------------------------------------------------------------
extern "C" void kernel_launch(void* const* d_in, const int* in_sizes, int n_in,
                              void* d_out, int out_size, void* d_ws, size_t ws_size,
                              hipStream_t stream)
{
    const float* x      = (const float*)d_in[0];
    const float* fc_w   = (const float*)d_in[1];
    const float* fc_b   = (const float*)d_in[2];
    const float* gamma  = (const float*)d_in[3];
    const float* beta   = (const float*)d_in[4];
    const float* fc2_w  = (const float*)d_in[5];
    const float* fc2_b  = (const float*)d_in[6];

    constexpr int N = 8192;
    constexpr int H = 128;

    float* qij   = (float*)d_out;                          // [N, N]
    float* o_out = (float*)d_out + (size_t)N * N;          // [N, 2]

    char* ws = (char*)d_ws;
    constexpr size_t O1_OFF     = 0;                       // N*H floats = 4 MB
    constexpr size_t SUMS_OFF   = (size_t)N * H * 4;       // 128 doubles
    constexpr size_t SUMSQ_OFF  = SUMS_OFF + 128 * 8;
    constexpr size_t DENOM_OFF  = SUMSQ_OFF + 128 * 8;
    constexpr size_t PACKED_OFF = DENOM_OFF + 16;          // N float4 = 128 KB

    float*  o1     = (float*)(ws + O1_OFF);
    double* sums   = (double*)(ws + SUMS_OFF);
    double* sumsq  = (double*)(ws + SUMSQ_OFF);
    double* denom  = (double*)(ws + DENOM_OFF);
    float4* packed = (float4*)(ws + PACKED_OFF);

    // zero the accumulators (ws is poisoned / stale between calls)
    hipMemsetAsync(ws + SUMS_OFF, 0, 128 * 8 * 2 + 16, stream);

    // A: o1 = selu(x @ fc_w^T + fc_b)
    gemm1_selu<<<dim3(N / 64, H / 64), 256, 0, stream>>>(x, fc_w, fc_b, o1);

    // B: column stats
    bn_stats<<<N / 64, 256, 0, stream>>>(o1, sums, sumsq);

    // C: normalize + fc2 + selu -> o_out, packed
    bn_fc2_selu<<<N / 4, 256, 0, stream>>>(o1, sums, sumsq, gamma, beta, fc2_w, fc2_b, o_out, packed);

    // D: denom = sum over all pairs of 1/(1+dis)
    denom_reduce<<<dim3(N / 64, N / 1024), 256, 0, stream>>>(packed, denom);

    // E: qij = (1/(denom - N)) / (1 + dis)
    qij_write<<<dim3(N / 32, N / 1024), 256, 0, stream>>>(packed, denom, qij);
}

// Round 4
// 128.000 us; speedup vs baseline: 1.6089x; 1.1814x over previous
//
#include <hip/hip_runtime.h>
#include <hip/hip_bf16.h>

#define SELU_L 1.0507009873554805f
#define SELU_A 1.6732632423543772f

typedef float floatx4 __attribute__((ext_vector_type(4)));

__device__ __forceinline__ float selu(float x) {
    return x > 0.f ? SELU_L * x : SELU_L * SELU_A * (expf(x) - 1.f);
}

__device__ __forceinline__ float fast_rcp(float x) {
    return __builtin_amdgcn_rcpf(x);
}

// ---------------- Kernel I: zero the stat accumulators ----------------------
__global__ __launch_bounds__(64) void init_accum(double* __restrict__ acc)
{
    // acc layout: sums[128], sumsq[128], denom[1]
    const int t = threadIdx.x;
#pragma unroll
    for (int i = t; i < 257; i += 64) acc[i] = 0.0;
}

// ---------------- Kernel A: o1 = selu(x @ fc_w^T + fc_b) --------------------
// x: [8192, 784], fc_w: [128, 784], o1: [8192, 128]
// BM=64, BN=64, BK=16, 256 threads (16x16), 4x4 per thread.
// Software-pipelined staging: next K-tile loads issue before compute.
__global__ __launch_bounds__(256) void gemm1_selu(
    const float* __restrict__ x, const float* __restrict__ w,
    const float* __restrict__ b, float* __restrict__ o1)
{
    __shared__ float As[16][68];
    __shared__ float Bs[16][68];
    const int bm = blockIdx.x * 64;
    const int bn = blockIdx.y * 64;
    const int t  = threadIdx.x;
    const int tx = t % 16, ty = t / 16;

    const int lrow  = t / 4;        // 0..63
    const int lcol4 = (t % 4) * 4;  // 0,4,8,12

    const float* xp = &x[(size_t)(bm + lrow) * 784 + lcol4];
    const float* wp = &w[(size_t)(bn + lrow) * 784 + lcol4];

    float acc[4][4] = {};

    float4 av = *reinterpret_cast<const float4*>(xp);
    float4 bv = *reinterpret_cast<const float4*>(wp);

    for (int k0 = 0; k0 < 784; k0 += 16) {
        As[lcol4 + 0][lrow] = av.x;
        As[lcol4 + 1][lrow] = av.y;
        As[lcol4 + 2][lrow] = av.z;
        As[lcol4 + 3][lrow] = av.w;
        Bs[lcol4 + 0][lrow] = bv.x;
        Bs[lcol4 + 1][lrow] = bv.y;
        Bs[lcol4 + 2][lrow] = bv.z;
        Bs[lcol4 + 3][lrow] = bv.w;
        __syncthreads();

        // prefetch next tile (clamped address on the last iter; value unused)
        const int kn = (k0 + 16 < 784) ? k0 + 16 : 0;
        av = *reinterpret_cast<const float4*>(xp + kn);
        bv = *reinterpret_cast<const float4*>(wp + kn);

#pragma unroll
        for (int kk = 0; kk < 16; ++kk) {
            float a[4], bb[4];
#pragma unroll
            for (int i = 0; i < 4; ++i) a[i] = As[kk][ty * 4 + i];
#pragma unroll
            for (int j = 0; j < 4; ++j) bb[j] = Bs[kk][tx * 4 + j];
#pragma unroll
            for (int i = 0; i < 4; ++i)
#pragma unroll
                for (int j = 0; j < 4; ++j)
                    acc[i][j] = fmaf(a[i], bb[j], acc[i][j]);
        }
        __syncthreads();
    }

#pragma unroll
    for (int i = 0; i < 4; ++i) {
        const int r = bm + ty * 4 + i;
#pragma unroll
        for (int j = 0; j < 4; ++j) {
            const int h = bn + tx * 4 + j;
            o1[(size_t)r * 128 + h] = selu(acc[i][j] + b[h]);
        }
    }
}

// ---------------- Kernel B: per-column sum / sumsq --------------------------
__global__ __launch_bounds__(256) void bn_stats(
    const float* __restrict__ o1, double* __restrict__ sums, double* __restrict__ sumsq)
{
    const int t   = threadIdx.x;
    const int col = t % 128;
    const int rh  = t / 128;
    const int base = blockIdx.x * 64;
    float s = 0.f, s2 = 0.f;
    for (int r = rh; r < 64; r += 2) {
        float v = o1[(size_t)(base + r) * 128 + col];
        s += v;
        s2 = fmaf(v, v, s2);
    }
    __shared__ float sh[256], sh2[256];
    sh[t] = s; sh2[t] = s2;
    __syncthreads();
    if (rh == 0) {
        s  = sh[t] + sh[t + 128];
        s2 = sh2[t] + sh2[t + 128];
        atomicAdd(&sums[col],  (double)s);
        atomicAdd(&sumsq[col], (double)s2);
    }
}

// ---------------- Kernel C: BN normalize + fc2 + selu -----------------------
// writes o_out [N,2] (tail of d_out) and packed [N] float4 = (o0, o1, sq, 0)
__global__ __launch_bounds__(256) void bn_fc2_selu(
    const float* __restrict__ o1, const double* __restrict__ sums, const double* __restrict__ sumsq,
    const float* __restrict__ gamma, const float* __restrict__ beta,
    const float* __restrict__ fc2w, const float* __restrict__ fc2b,
    float* __restrict__ o_out, float4* __restrict__ packed)
{
    const int wave = threadIdx.x >> 6;
    const int lane = threadIdx.x & 63;
    const int row  = blockIdx.x * 4 + wave;

    float d0 = 0.f, d1 = 0.f;
#pragma unroll
    for (int half = 0; half < 2; ++half) {
        const int col = lane + half * 64;
        const float mu  = (float)(sums[col]  * (1.0 / 8192.0));
        const float ex2 = (float)(sumsq[col] * (1.0 / 8192.0));
        const float var = ex2 - mu * mu;
        const float inv = rsqrtf(var + 1e-5f);
        const float v = (o1[(size_t)row * 128 + col] - mu) * inv * gamma[col] + beta[col];
        d0 = fmaf(v, fc2w[col],       d0);
        d1 = fmaf(v, fc2w[128 + col], d1);
    }
#pragma unroll
    for (int off = 32; off >= 1; off >>= 1) {
        d0 += __shfl_down(d0, off);
        d1 += __shfl_down(d1, off);
    }
    if (lane == 0) {
        const float y0 = selu(d0 + fc2b[0]);
        const float y1 = selu(d1 + fc2b[1]);
        o_out[(size_t)row * 2 + 0] = y0;
        o_out[(size_t)row * 2 + 1] = y1;
        packed[row] = make_float4(y0, y1, y0 * y0 + y1 * y1, 0.f);
    }
}

// ---------------- Kernel D: denom = 2 * sum_{i<j} 1/(1+dis) -----------------
// grid (128, 8): 64 rows x 1024 cols per block; triangular skip/predicate.
__global__ __launch_bounds__(256) void denom_reduce(
    const float4* __restrict__ packed, double* __restrict__ denom)
{
    const int rb = blockIdx.x * 64;
    const int cb = blockIdx.y * 1024;
    if (cb + 1024 <= rb) return;            // whole block has j < i -> no pairs

    const int t = threadIdx.x;
    const bool full = (cb >= rb + 64);      // whole block has j > i

    float4 cd[4];
#pragma unroll
    for (int u = 0; u < 4; ++u) cd[u] = packed[cb + t + u * 256];

    float accf = 0.f;
#pragma unroll 4
    for (int r = 0; r < 64; ++r) {
        const int i = rb + r;
        const float4 pi = packed[i];        // uniform address -> scalar load
#pragma unroll
        for (int u = 0; u < 4; ++u) {
            float dis = pi.z + cd[u].z - 2.f * fmaf(pi.x, cd[u].x, pi.y * cd[u].y);
            dis = fmaxf(dis, 0.f);
            float f = fast_rcp(1.f + dis);
            if (!full) {
                const int j = cb + t + u * 256;
                f = (j > i) ? f : 0.f;
            }
            accf += f;
        }
    }
    // wave reduce (float), then block reduce in double, one atomic per block
#pragma unroll
    for (int off = 32; off >= 1; off >>= 1) accf += __shfl_down(accf, off);
    __shared__ double wsum[4];
    const int wave = t >> 6, lane = t & 63;
    if (lane == 0) wsum[wave] = (double)accf;
    __syncthreads();
    if (t == 0) {
        double v = wsum[0] + wsum[1] + wsum[2] + wsum[3];
        atomicAdd(denom, 2.0 * v);          // full denom = 2 * sum_{i<j}
    }
}

// ---------------- Kernel E: qij = inv_denom / (1 + dis), nt float4 stores ---
// grid (256, 8): 32 rows x 1024 cols per block. Column data in REGISTERS.
__global__ __launch_bounds__(256) void qij_write(
    const float4* __restrict__ packed, const double* __restrict__ denom,
    float* __restrict__ qij)
{
    const int t  = threadIdx.x;
    const int cb = blockIdx.y * 1024;

    float4 cd[4];
#pragma unroll
    for (int u = 0; u < 4; ++u) cd[u] = packed[cb + t * 4 + u];

    const float inv = (float)(1.0 / denom[0]);

    const int rb = blockIdx.x * 32;
#pragma unroll 4
    for (int r = 0; r < 32; ++r) {
        const int i = rb + r;
        const float4 pi = packed[i];        // uniform address -> scalar load
        floatx4 q;
#pragma unroll
        for (int u = 0; u < 4; ++u) {
            float dis = pi.z + cd[u].z - 2.f * fmaf(pi.x, cd[u].x, pi.y * cd[u].y);
            dis = fmaxf(dis, 0.f);
            q[u] = inv * fast_rcp(1.f + dis);
        }
        __builtin_nontemporal_store(
            q, reinterpret_cast<floatx4*>(&qij[(size_t)i * 8192 + cb + t * 4]));
    }
}

// ---------------------------------------------------------------------------
extern "C" void kernel_launch(void* const* d_in, const int* in_sizes, int n_in,
                              void* d_out, int out_size, void* d_ws, size_t ws_size,
                              hipStream_t stream)
{
    const float* x      = (const float*)d_in[0];
    const float* fc_w   = (const float*)d_in[1];
    const float* fc_b   = (const float*)d_in[2];
    const float* gamma  = (const float*)d_in[3];
    const float* beta   = (const float*)d_in[4];
    const float* fc2_w  = (const float*)d_in[5];
    const float* fc2_b  = (const float*)d_in[6];

    constexpr int N = 8192;
    constexpr int H = 128;

    float* qij   = (float*)d_out;                          // [N, N]
    float* o_out = (float*)d_out + (size_t)N * N;          // [N, 2]

    char* ws = (char*)d_ws;
    constexpr size_t O1_OFF     = 0;                       // N*H floats = 4 MB
    constexpr size_t ACC_OFF    = (size_t)N * H * 4;       // 257 doubles
    constexpr size_t PACKED_OFF = ACC_OFF + 257 * 8 + 8;   // N float4 = 128 KB

    float*  o1     = (float*)(ws + O1_OFF);
    double* accs   = (double*)(ws + ACC_OFF);              // sums|sumsq|denom
    double* sums   = accs;
    double* sumsq  = accs + 128;
    double* denom  = accs + 256;
    float4* packed = (float4*)(ws + PACKED_OFF);

    // I: zero accumulators (replaces hipMemsetAsync)
    init_accum<<<1, 64, 0, stream>>>(accs);

    // A: o1 = selu(x @ fc_w^T + fc_b)
    gemm1_selu<<<dim3(N / 64, H / 64), 256, 0, stream>>>(x, fc_w, fc_b, o1);

    // B: column stats
    bn_stats<<<N / 64, 256, 0, stream>>>(o1, sums, sumsq);

    // C: normalize + fc2 + selu -> o_out, packed
    bn_fc2_selu<<<N / 4, 256, 0, stream>>>(o1, sums, sumsq, gamma, beta, fc2_w, fc2_b, o_out, packed);

    // D: denom = 2 * sum_{i<j} 1/(1+dis)
    denom_reduce<<<dim3(N / 64, N / 1024), 256, 0, stream>>>(packed, denom);

    // E: qij = (1/denom) / (1 + dis)
    qij_write<<<dim3(N / 32, N / 1024), 256, 0, stream>>>(packed, denom, qij);
}

// Round 5
// 117.609 us; speedup vs baseline: 1.7511x; 1.0883x over previous
//
#include <hip/hip_runtime.h>
#include <hip/hip_bf16.h>

#define SELU_L 1.0507009873554805f
#define SELU_A 1.6732632423543772f

typedef float floatx4 __attribute__((ext_vector_type(4)));

__device__ __forceinline__ float selu(float x) {
    return x > 0.f ? SELU_L * x : SELU_L * SELU_A * (expf(x) - 1.f);
}

__device__ __forceinline__ float fast_rcp(float x) {
    return __builtin_amdgcn_rcpf(x);
}

// ---------------- Kernel I: zero the stat accumulators ----------------------
__global__ __launch_bounds__(64) void init_accum(double* __restrict__ acc)
{
    // acc layout: sums[128], sumsq[128], denom[1]
    const int t = threadIdx.x;
#pragma unroll
    for (int i = t; i < 257; i += 64) acc[i] = 0.0;
}

// ---------------- Kernel A: o1 = selu(x @ fc_w^T + fc_b) + column stats -----
// x: [8192, 784], fc_w: [128, 784], o1: [8192, 128]
// BM=64, BN=64, BK=16, 512 threads (8 waves -> 2 waves/SIMD), 2x4 per thread.
// Threads <256 stage the x-tile, >=256 stage the w-tile (one float4 each).
// Epilogue: per-block column sum/sumsq reduced in LDS, one double atomic per
// column per block (replaces the old bn_stats kernel).
__global__ __launch_bounds__(512) void gemm1_selu_stats(
    const float* __restrict__ x, const float* __restrict__ w,
    const float* __restrict__ b, float* __restrict__ o1,
    double* __restrict__ sums, double* __restrict__ sumsq)
{
    __shared__ float As[16][68];
    __shared__ float Bs[16][68];
    __shared__ float red[32][64];

    const int bm = blockIdx.x * 64;
    const int bn = blockIdx.y * 64;
    const int t  = threadIdx.x;
    const int tx = t & 15;          // col group (4 cols)
    const int ty = t >> 4;          // row group (2 rows), 0..31

    // staging assignment
    const int  srow   = (t & 255) >> 2;      // 0..63
    const int  scol4  = (t & 3) * 4;         // 0,4,8,12
    const bool stageW = (t >= 256);
    const float* sp = stageW ? &w[(size_t)(bn + srow) * 784 + scol4]
                             : &x[(size_t)(bm + srow) * 784 + scol4];
    float (*St)[68] = stageW ? Bs : As;

    float4 v = *reinterpret_cast<const float4*>(sp);
    float acc[2][4] = {};

    for (int k0 = 0; k0 < 784; k0 += 16) {
        St[scol4 + 0][srow] = v.x;
        St[scol4 + 1][srow] = v.y;
        St[scol4 + 2][srow] = v.z;
        St[scol4 + 3][srow] = v.w;
        __syncthreads();

        // prefetch next tile (clamped address on last iter; value unused)
        const int kn = (k0 + 16 < 784) ? k0 + 16 : 0;
        v = *reinterpret_cast<const float4*>(sp + kn);

#pragma unroll
        for (int kk = 0; kk < 16; ++kk) {
            float a[2], bb[4];
#pragma unroll
            for (int i = 0; i < 2; ++i) a[i] = As[kk][ty * 2 + i];
#pragma unroll
            for (int j = 0; j < 4; ++j) bb[j] = Bs[kk][tx * 4 + j];
#pragma unroll
            for (int i = 0; i < 2; ++i)
#pragma unroll
                for (int j = 0; j < 4; ++j)
                    acc[i][j] = fmaf(a[i], bb[j], acc[i][j]);
        }
        __syncthreads();
    }

    // epilogue: bias + selu, vectorized store, column partials
    float s[4] = {}, s2[4] = {};
#pragma unroll
    for (int i = 0; i < 2; ++i) {
        const int r = bm + ty * 2 + i;
        floatx4 ov;
#pragma unroll
        for (int j = 0; j < 4; ++j) {
            const int h = bn + tx * 4 + j;
            const float val = selu(acc[i][j] + b[h]);
            ov[j] = val;
            s[j] += val;
            s2[j] = fmaf(val, val, s2[j]);
        }
        *reinterpret_cast<floatx4*>(&o1[(size_t)r * 128 + bn + tx * 4]) = ov;
    }

    // reduce column partials over the 32 ty-groups
#pragma unroll
    for (int j = 0; j < 4; ++j) red[ty][tx * 4 + j] = s[j];
    __syncthreads();
    float tot = 0.f;
    if (t < 64) {
#pragma unroll
        for (int k = 0; k < 32; ++k) tot += red[k][t];
    }
    __syncthreads();
#pragma unroll
    for (int j = 0; j < 4; ++j) red[ty][tx * 4 + j] = s2[j];
    __syncthreads();
    if (t < 64) {
        float tot2 = 0.f;
#pragma unroll
        for (int k = 0; k < 32; ++k) tot2 += red[k][t];
        atomicAdd(&sums[bn + t],  (double)tot);
        atomicAdd(&sumsq[bn + t], (double)tot2);
    }
}

// ---------------- Kernel C: BN normalize + fc2 + selu -----------------------
// writes o_out [N,2] (tail of d_out) and packed [N] float4 = (o0, o1, sq, 0)
__global__ __launch_bounds__(256) void bn_fc2_selu(
    const float* __restrict__ o1, const double* __restrict__ sums, const double* __restrict__ sumsq,
    const float* __restrict__ gamma, const float* __restrict__ beta,
    const float* __restrict__ fc2w, const float* __restrict__ fc2b,
    float* __restrict__ o_out, float4* __restrict__ packed)
{
    const int wave = threadIdx.x >> 6;
    const int lane = threadIdx.x & 63;
    const int row  = blockIdx.x * 4 + wave;

    float d0 = 0.f, d1 = 0.f;
#pragma unroll
    for (int half = 0; half < 2; ++half) {
        const int col = lane + half * 64;
        const float mu  = (float)(sums[col]  * (1.0 / 8192.0));
        const float ex2 = (float)(sumsq[col] * (1.0 / 8192.0));
        const float var = ex2 - mu * mu;
        const float inv = rsqrtf(var + 1e-5f);
        const float v = (o1[(size_t)row * 128 + col] - mu) * inv * gamma[col] + beta[col];
        d0 = fmaf(v, fc2w[col],       d0);
        d1 = fmaf(v, fc2w[128 + col], d1);
    }
#pragma unroll
    for (int off = 32; off >= 1; off >>= 1) {
        d0 += __shfl_down(d0, off);
        d1 += __shfl_down(d1, off);
    }
    if (lane == 0) {
        const float y0 = selu(d0 + fc2b[0]);
        const float y1 = selu(d1 + fc2b[1]);
        o_out[(size_t)row * 2 + 0] = y0;
        o_out[(size_t)row * 2 + 1] = y1;
        packed[row] = make_float4(y0, y1, y0 * y0 + y1 * y1, 0.f);
    }
}

// ---------------- Kernel D: denom = 2 * sum_{i<j} 1/(1+dis) -----------------
// grid (128, 8): 64 rows x 1024 cols per block; triangular skip/predicate.
__global__ __launch_bounds__(256) void denom_reduce(
    const float4* __restrict__ packed, double* __restrict__ denom)
{
    const int rb = blockIdx.x * 64;
    const int cb = blockIdx.y * 1024;
    if (cb + 1024 <= rb) return;            // whole block has j < i -> no pairs

    const int t = threadIdx.x;
    const bool full = (cb >= rb + 64);      // whole block has j > i

    float4 cd[4];
#pragma unroll
    for (int u = 0; u < 4; ++u) cd[u] = packed[cb + t + u * 256];

    float accf = 0.f;
#pragma unroll 4
    for (int r = 0; r < 64; ++r) {
        const int i = rb + r;
        const float4 pi = packed[i];        // uniform address -> scalar load
#pragma unroll
        for (int u = 0; u < 4; ++u) {
            float dis = pi.z + cd[u].z - 2.f * fmaf(pi.x, cd[u].x, pi.y * cd[u].y);
            dis = fmaxf(dis, 0.f);
            float f = fast_rcp(1.f + dis);
            if (!full) {
                const int j = cb + t + u * 256;
                f = (j > i) ? f : 0.f;
            }
            accf += f;
        }
    }
    // wave reduce (float), then block reduce in double, one atomic per block
#pragma unroll
    for (int off = 32; off >= 1; off >>= 1) accf += __shfl_down(accf, off);
    __shared__ double wsum[4];
    const int wave = t >> 6, lane = t & 63;
    if (lane == 0) wsum[wave] = (double)accf;
    __syncthreads();
    if (t == 0) {
        double v = wsum[0] + wsum[1] + wsum[2] + wsum[3];
        atomicAdd(denom, 2.0 * v);          // full denom = 2 * sum_{i<j}
    }
}

// ---------------- Kernel E: qij = inv_denom / (1 + dis), nt float4 stores ---
// grid (256, 8): 32 rows x 1024 cols per block. Column data in REGISTERS.
__global__ __launch_bounds__(256) void qij_write(
    const float4* __restrict__ packed, const double* __restrict__ denom,
    float* __restrict__ qij)
{
    const int t  = threadIdx.x;
    const int cb = blockIdx.y * 1024;

    float4 cd[4];
#pragma unroll
    for (int u = 0; u < 4; ++u) cd[u] = packed[cb + t * 4 + u];

    const float inv = (float)(1.0 / denom[0]);

    const int rb = blockIdx.x * 32;
#pragma unroll 4
    for (int r = 0; r < 32; ++r) {
        const int i = rb + r;
        const float4 pi = packed[i];        // uniform address -> scalar load
        floatx4 q;
#pragma unroll
        for (int u = 0; u < 4; ++u) {
            float dis = pi.z + cd[u].z - 2.f * fmaf(pi.x, cd[u].x, pi.y * cd[u].y);
            dis = fmaxf(dis, 0.f);
            q[u] = inv * fast_rcp(1.f + dis);
        }
        __builtin_nontemporal_store(
            q, reinterpret_cast<floatx4*>(&qij[(size_t)i * 8192 + cb + t * 4]));
    }
}

// ---------------------------------------------------------------------------
extern "C" void kernel_launch(void* const* d_in, const int* in_sizes, int n_in,
                              void* d_out, int out_size, void* d_ws, size_t ws_size,
                              hipStream_t stream)
{
    const float* x      = (const float*)d_in[0];
    const float* fc_w   = (const float*)d_in[1];
    const float* fc_b   = (const float*)d_in[2];
    const float* gamma  = (const float*)d_in[3];
    const float* beta   = (const float*)d_in[4];
    const float* fc2_w  = (const float*)d_in[5];
    const float* fc2_b  = (const float*)d_in[6];

    constexpr int N = 8192;

    float* qij   = (float*)d_out;                          // [N, N]
    float* o_out = (float*)d_out + (size_t)N * N;          // [N, 2]

    char* ws = (char*)d_ws;
    constexpr size_t O1_OFF     = 0;                       // N*128 floats = 4 MB
    constexpr size_t ACC_OFF    = (size_t)N * 128 * 4;     // 257 doubles
    constexpr size_t PACKED_OFF = ACC_OFF + 257 * 8 + 8;   // N float4 = 128 KB

    float*  o1     = (float*)(ws + O1_OFF);
    double* accs   = (double*)(ws + ACC_OFF);              // sums|sumsq|denom
    double* sums   = accs;
    double* sumsq  = accs + 128;
    double* denom  = accs + 256;
    float4* packed = (float4*)(ws + PACKED_OFF);

    // I: zero accumulators
    init_accum<<<1, 64, 0, stream>>>(accs);

    // A: o1 = selu(x @ fc_w^T + fc_b), fused column stats
    gemm1_selu_stats<<<dim3(N / 64, 2), 512, 0, stream>>>(x, fc_w, fc_b, o1, sums, sumsq);

    // C: normalize + fc2 + selu -> o_out, packed
    bn_fc2_selu<<<N / 4, 256, 0, stream>>>(o1, sums, sumsq, gamma, beta, fc2_w, fc2_b, o_out, packed);

    // D: denom = 2 * sum_{i<j} 1/(1+dis)
    denom_reduce<<<dim3(N / 64, N / 1024), 256, 0, stream>>>(packed, denom);

    // E: qij = (1/denom) / (1 + dis)
    qij_write<<<dim3(N / 32, N / 1024), 256, 0, stream>>>(packed, denom, qij);
}